// Round 1
// baseline (1225.340 us; speedup 1.0000x reference)
//
#include <hip/hip_runtime.h>
#include <stdint.h>

constexpr int NB = 128; // batch

// ---------------- weight sign packing ----------------
// out[(oc*9 + t)*ICW + iw], bit b = (w[(oc*IC + iw*32 + b)*9 + t] > 0)
__global__ void pack_weights_kernel(const float* __restrict__ w, uint32_t* __restrict__ out,
                                    int OC, int ICW)
{
    int idx = blockIdx.x * blockDim.x + threadIdx.x;
    int total = OC * 9 * ICW;
    if (idx >= total) return;
    int iw = idx % ICW;
    int t  = (idx / ICW) % 9;
    int oc = idx / (9 * ICW);
    int IC = ICW * 32;
    uint32_t word = 0;
    for (int b = 0; b < 32; ++b) {
        float wv = w[(size_t)(oc * IC + (iw * 32 + b)) * 9 + t];
        word |= (wv > 0.f ? 1u : 0u) << b;
    }
    out[idx] = word;
}

// ---------------- stage 1: full-precision conv 1->32 ----------------
__device__ __forceinline__ void conv1_load9(const float* __restrict__ x, int p, float* xv)
{
    int n = p >> 14;
    int y = (p >> 7) & 127;
    int c = p & 127;
    const float* xn = x + (size_t)n * 16384;
    #pragma unroll
    for (int ky = 0; ky < 3; ++ky)
    #pragma unroll
    for (int kx = 0; kx < 3; ++kx) {
        int yy = y + ky - 1, cc = c + kx - 1;
        float v = 0.f;
        if (yy >= 0 && yy < 128 && cc >= 0 && cc < 128) v = xn[yy * 128 + cc];
        xv[ky * 3 + kx] = v;
    }
}

__global__ __launch_bounds__(256) void conv1_stats_kernel(
    const float* __restrict__ x, const float* __restrict__ w1, const float* __restrict__ b1,
    float* __restrict__ partials)
{
    __shared__ float wl[320];
    __shared__ float wbuf[4][64];
    int tid = threadIdx.x;
    for (int i = tid; i < 320; i += 256) wl[i] = (i < 288) ? w1[i] : b1[i - 288];
    __syncthreads();

    float xv[4][9];
    int base = blockIdx.x * 256 + tid;
    #pragma unroll
    for (int i = 0; i < 4; ++i) conv1_load9(x, base + i * 524288, xv[i]);

    float sum[32], sq[32];
    #pragma unroll
    for (int oc = 0; oc < 32; ++oc) {
        float w[9];
        #pragma unroll
        for (int t = 0; t < 9; ++t) w[t] = wl[oc * 9 + t];
        float b = wl[288 + oc];
        float s = 0.f, s2 = 0.f;
        #pragma unroll
        for (int i = 0; i < 4; ++i) {
            float a = b;
            #pragma unroll
            for (int t = 0; t < 9; ++t) a = fmaf(xv[i][t], w[t], a);
            s += a; s2 = fmaf(a, a, s2);
        }
        sum[oc] = s; sq[oc] = s2;
    }
    #pragma unroll
    for (int oc = 0; oc < 32; ++oc) {
        float s = sum[oc], s2 = sq[oc];
        #pragma unroll
        for (int off = 32; off >= 1; off >>= 1) {
            s  += __shfl_xor(s,  off, 64);
            s2 += __shfl_xor(s2, off, 64);
        }
        sum[oc] = s; sq[oc] = s2;
    }
    int lane = tid & 63, wv = tid >> 6;
    if (lane == 0) {
        #pragma unroll
        for (int oc = 0; oc < 32; ++oc) { wbuf[wv][oc] = sum[oc]; wbuf[wv][32 + oc] = sq[oc]; }
    }
    __syncthreads();
    if (tid < 64)
        partials[blockIdx.x * 64 + tid] = wbuf[0][tid] + wbuf[1][tid] + wbuf[2][tid] + wbuf[3][tid];
}

__global__ __launch_bounds__(256) void conv1_pack_kernel(
    const float* __restrict__ x, const float* __restrict__ w1, const float* __restrict__ b1,
    const float* __restrict__ ss, uint32_t* __restrict__ s1)
{
    __shared__ float wl[384];
    int tid = threadIdx.x;
    for (int i = tid; i < 384; i += 256)
        wl[i] = (i < 288) ? w1[i] : ((i < 320) ? b1[i - 288] : ss[i - 320]);
    __syncthreads();

    float xv[4][9];
    int base = blockIdx.x * 256 + tid;
    #pragma unroll
    for (int i = 0; i < 4; ++i) conv1_load9(x, base + i * 524288, xv[i]);

    uint32_t word[4] = {0, 0, 0, 0};
    #pragma unroll
    for (int oc = 0; oc < 32; ++oc) {
        float w[9];
        #pragma unroll
        for (int t = 0; t < 9; ++t) w[t] = wl[oc * 9 + t];
        float b = wl[288 + oc];
        float A = wl[320 + oc], B = wl[352 + oc];
        #pragma unroll
        for (int i = 0; i < 4; ++i) {
            float a = b;
            #pragma unroll
            for (int t = 0; t < 9; ++t) a = fmaf(xv[i][t], w[t], a);
            float v = fmaf(A, a, B);
            word[i] |= (v > 0.f ? 1u : 0u) << oc;
        }
    }
    #pragma unroll
    for (int i = 0; i < 4; ++i) s1[base + i * 524288] = word[i];
}

// ---------------- BN finalize: partials -> per-channel scale/shift ----------------
template<int OC>
__global__ void finalize_stats_kernel(const float* __restrict__ partials, int nblk,
                                      const float* __restrict__ gamma, const float* __restrict__ beta,
                                      float inv_n, float* __restrict__ ss)
{
    __shared__ float sums[2 * OC];
    int tid = threadIdx.x;
    if (tid < 2 * OC) {
        double a = 0.0;
        for (int i = 0; i < nblk; ++i) a += (double)partials[(size_t)i * (2 * OC) + tid];
        sums[tid] = (float)a;
    }
    __syncthreads();
    if (tid < OC) {
        float mu  = sums[tid] * inv_n;
        float ex2 = sums[OC + tid] * inv_n;
        float var = ex2 - mu * mu;
        float rs  = 1.f / sqrtf(var + 1e-5f);
        float A = gamma[tid] * rs;
        ss[tid] = A;
        ss[OC + tid] = beta[tid] - mu * A;
    }
}

// ---------------- binary conv (xnor-popcount) + 2x2 maxpool ----------------
// MODE 0: accumulate per-channel sum/sumsq of pooled values -> partials
// MODE 1: apply BN scale/shift, sign, pack bits -> sout
template<int OC, int W, int P, int MODE, int G>
__global__ __launch_bounds__(256) void binconv_pool_kernel(
    const uint32_t* __restrict__ sin, const uint32_t* __restrict__ wp,
    const float* __restrict__ alpha, const float* __restrict__ ss,
    float* __restrict__ partials, void* __restrict__ sout)
{
    constexpr int PW = W / 2;
    constexpr int TOTAL = NB * PW * PW;
    constexpr int STRIDE = TOTAL / P;
    static_assert(TOTAL % (256 * P) == 0, "grid divisibility");
    static_assert(OC % G == 0, "group divisibility");

    __shared__ uint32_t wl[OC * 9];
    __shared__ float ssl[2 * OC];
    __shared__ float wbuf[4][2 * OC];

    int tid = threadIdx.x;
    for (int i = tid; i < OC * 9; i += 256) wl[i] = wp[i];
    if constexpr (MODE == 1) { if (tid < 2 * OC) ssl[tid] = ss[tid]; }
    __syncthreads();
    float alp = alpha[0];
    int base = blockIdx.x * 256 + tid;

    uint32_t xw[P][16];
    uint32_t wm[P][16];
    int cnt[P][4];
    int pidx[P];
    #pragma unroll
    for (int i = 0; i < P; ++i) {
        int p = base + i * STRIDE;
        pidx[i] = p;
        int n = p / (PW * PW);
        int rem = p % (PW * PW);
        int py = rem / PW, px = rem % PW;
        int r0 = 2 * py - 1, c0 = 2 * px - 1;
        const uint32_t* sp = sin + (size_t)n * W * W;
        #pragma unroll
        for (int a = 0; a < 4; ++a) {
            int r = r0 + a;
            bool rv = (r >= 0) & (r < W);
            #pragma unroll
            for (int b = 0; b < 4; ++b) {
                int c = c0 + b;
                bool v = rv & (c >= 0) & (c < W);
                wm[i][a * 4 + b] = v ? 0xFFFFFFFFu : 0u;
                xw[i][a * 4 + b] = v ? sp[r * W + c] : 0u;
            }
        }
        #pragma unroll
        for (int a2 = 0; a2 < 2; ++a2)
        #pragma unroll
        for (int b2 = 0; b2 < 2; ++b2) {
            int cc = 0;
            #pragma unroll
            for (int ky = 0; ky < 3; ++ky)
            #pragma unroll
            for (int kx = 0; kx < 3; ++kx)
                cc += (int)(wm[i][(a2 + ky) * 4 + (b2 + kx)] & 1u);
            cnt[i][a2 * 2 + b2] = cc * 32;
        }
    }

    uint64_t word[P];
    #pragma unroll
    for (int i = 0; i < P; ++i) word[i] = 0;

    for (int g = 0; g < OC / G; ++g) {   // runtime loop keeps icache small
        float s[G], s2[G];
        #pragma unroll
        for (int j = 0; j < G; ++j) { s[j] = 0.f; s2[j] = 0.f; }

        #pragma unroll
        for (int j = 0; j < G; ++j) {
            int oc = g * G + j;
            uint32_t w9[9];
            #pragma unroll
            for (int t = 0; t < 9; ++t) w9[t] = wl[oc * 9 + t];
            #pragma unroll
            for (int i = 0; i < P; ++i) {
                float m = -3.4e38f;
                #pragma unroll
                for (int a2 = 0; a2 < 2; ++a2)
                #pragma unroll
                for (int b2 = 0; b2 < 2; ++b2) {
                    int pop = 0;
                    #pragma unroll
                    for (int ky = 0; ky < 3; ++ky)
                    #pragma unroll
                    for (int kx = 0; kx < 3; ++kx) {
                        int idx = (a2 + ky) * 4 + (b2 + kx);
                        pop += __popc((xw[i][idx] ^ w9[ky * 3 + kx]) & wm[i][idx]);
                    }
                    float v = alp * (float)(cnt[i][a2 * 2 + b2] - 2 * pop);
                    m = fmaxf(m, v);
                }
                if constexpr (MODE == 0) {
                    s[j] += m; s2[j] = fmaf(m, m, s2[j]);
                } else {
                    float vv = fmaf(ssl[oc], m, ssl[OC + oc]);
                    word[i] |= (vv > 0.f ? 1ull : 0ull) << oc;
                }
            }
        }
        if constexpr (MODE == 0) {
            int lane = tid & 63, wv = tid >> 6;
            #pragma unroll
            for (int j = 0; j < G; ++j) {
                float a = s[j], b = s2[j];
                #pragma unroll
                for (int off = 32; off >= 1; off >>= 1) {
                    a += __shfl_xor(a, off, 64);
                    b += __shfl_xor(b, off, 64);
                }
                if (lane == 0) { wbuf[wv][g * G + j] = a; wbuf[wv][OC + g * G + j] = b; }
            }
        }
    }

    if constexpr (MODE == 1) {
        #pragma unroll
        for (int i = 0; i < P; ++i) {
            if constexpr (OC == 32) ((uint32_t*)sout)[pidx[i]] = (uint32_t)word[i];
            else                    ((uint64_t*)sout)[pidx[i]] = word[i];
        }
    } else {
        __syncthreads();
        if (tid < 2 * OC)
            partials[blockIdx.x * (2 * OC) + tid] =
                wbuf[0][tid] + wbuf[1][tid] + wbuf[2][tid] + wbuf[3][tid];
    }
}

// ---------------- stage 4: binary conv 64->128 + global mean ----------------
__global__ __launch_bounds__(256) void conv4_mean_kernel(
    const uint64_t* __restrict__ s3, const uint64_t* __restrict__ wp4,
    const float* __restrict__ alpha4, float* __restrict__ mean4)
{
    __shared__ uint64_t xt[1024];
    __shared__ uint64_t wl[1152];
    __shared__ float red[256];
    int n = blockIdx.x, tid = threadIdx.x;
    for (int i = tid; i < 1024; i += 256) xt[i] = s3[n * 1024 + i];
    for (int i = tid; i < 1152; i += 256) wl[i] = wp4[i];
    __syncthreads();
    int oc = tid & 127, h = tid >> 7;
    uint64_t wr[9];
    #pragma unroll
    for (int t = 0; t < 9; ++t) wr[t] = wl[oc * 9 + t];
    int acc = 0;
    for (int y = h * 16; y < h * 16 + 16; ++y) {
        for (int x = 0; x < 32; ++x) {
            int pop = 0, c = 0;
            #pragma unroll
            for (int ky = 0; ky < 3; ++ky) {
                int yy = y + ky - 1;
                if (yy < 0 || yy >= 32) continue;
                #pragma unroll
                for (int kx = 0; kx < 3; ++kx) {
                    int xx = x + kx - 1;
                    if (xx < 0 || xx >= 32) continue;
                    pop += __popcll(xt[yy * 32 + xx] ^ wr[ky * 3 + kx]);
                    c += 64;
                }
            }
            acc += c - 2 * pop;
        }
    }
    red[tid] = (float)acc;
    __syncthreads();
    if (tid < 128)
        mean4[n * 128 + tid] = (red[tid] + red[tid + 128]) * alpha4[0] * (1.f / 1024.f);
}

// ---------------- classifier ----------------
__global__ void linear_kernel(const float* __restrict__ mean4, const float* __restrict__ wf,
                              const float* __restrict__ bf, float* __restrict__ out)
{
    int t = blockIdx.x * blockDim.x + threadIdx.x;
    if (t >= 1280) return;
    int n = t / 10, k = t % 10;
    const float* m = mean4 + n * 128;
    const float* w = wf + k * 128;
    float a = bf[k];
    #pragma unroll 4
    for (int i = 0; i < 128; ++i) a = fmaf(m[i], w[i], a);
    out[t] = a;
}

extern "C" void kernel_launch(void* const* d_in, const int* in_sizes, int n_in,
                              void* d_out, int out_size, void* d_ws, size_t ws_size,
                              hipStream_t stream)
{
    const float* x   = (const float*)d_in[0];
    const float* w1  = (const float*)d_in[1];
    const float* b1  = (const float*)d_in[2];
    const float* g1  = (const float*)d_in[3];
    const float* be1 = (const float*)d_in[4];
    const float* w2  = (const float*)d_in[5];
    const float* a2  = (const float*)d_in[6];
    const float* g2  = (const float*)d_in[7];
    const float* be2 = (const float*)d_in[8];
    const float* w3  = (const float*)d_in[9];
    const float* a3  = (const float*)d_in[10];
    const float* g3  = (const float*)d_in[11];
    const float* be3 = (const float*)d_in[12];
    const float* w4  = (const float*)d_in[13];
    const float* a4  = (const float*)d_in[14];
    const float* wf  = (const float*)d_in[15];
    const float* bf  = (const float*)d_in[16];
    float* out = (float*)d_out;

    uint8_t* ws = (uint8_t*)d_ws;
    size_t off = 0;
    auto alloc = [&](size_t bytes) -> void* {
        void* p = ws + off;
        off += (bytes + 255) & ~(size_t)255;
        return p;
    };
    uint32_t* wp2 = (uint32_t*)alloc(288 * 4);
    uint32_t* wp3 = (uint32_t*)alloc(576 * 4);
    uint32_t* wp4 = (uint32_t*)alloc(2304 * 4);
    float* ss1 = (float*)alloc(64 * 4);
    float* ss2 = (float*)alloc(64 * 4);
    float* ss3 = (float*)alloc(128 * 4);
    uint32_t* s1 = (uint32_t*)alloc((size_t)128 * 128 * 128 * 4);
    uint32_t* s2 = (uint32_t*)alloc((size_t)128 * 64 * 64 * 4);
    uint64_t* s3 = (uint64_t*)alloc((size_t)128 * 32 * 32 * 8);
    float* mean4 = (float*)alloc((size_t)128 * 128 * 4);
    float* partials = (float*)alloc((size_t)2048 * 64 * 4);

    // pack weight signs
    pack_weights_kernel<<<2, 256, 0, stream>>>(w2, wp2, 32, 1);
    pack_weights_kernel<<<3, 256, 0, stream>>>(w3, wp3, 64, 1);
    pack_weights_kernel<<<9, 256, 0, stream>>>(w4, wp4, 128, 2);

    // stage 1: fp conv -> BN stats -> sign+pack
    conv1_stats_kernel<<<2048, 256, 0, stream>>>(x, w1, b1, partials);
    finalize_stats_kernel<32><<<1, 128, 0, stream>>>(partials, 2048, g1, be1, 1.f / 2097152.f, ss1);
    conv1_pack_kernel<<<2048, 256, 0, stream>>>(x, w1, b1, ss1, s1);

    // stage 2: binconv 32->32 @128 + pool -> BN -> sign+pack
    binconv_pool_kernel<32, 128, 2, 0, 4><<<1024, 256, 0, stream>>>(s1, wp2, a2, nullptr, partials, nullptr);
    finalize_stats_kernel<32><<<1, 128, 0, stream>>>(partials, 1024, g2, be2, 1.f / 524288.f, ss2);
    binconv_pool_kernel<32, 128, 2, 1, 4><<<1024, 256, 0, stream>>>(s1, wp2, a2, ss2, nullptr, (void*)s2);

    // stage 3: binconv 32->64 @64 + pool -> BN -> sign+pack
    binconv_pool_kernel<64, 64, 2, 0, 4><<<256, 256, 0, stream>>>(s2, wp3, a3, nullptr, partials, nullptr);
    finalize_stats_kernel<64><<<1, 128, 0, stream>>>(partials, 256, g3, be3, 1.f / 131072.f, ss3);
    binconv_pool_kernel<64, 64, 2, 1, 4><<<256, 256, 0, stream>>>(s2, wp3, a3, ss3, nullptr, (void*)s3);

    // stage 4: binconv 64->128 @32 + global mean, then classifier
    conv4_mean_kernel<<<128, 256, 0, stream>>>(s3, (const uint64_t*)wp4, a4, mean4);
    linear_kernel<<<5, 256, 0, stream>>>(mean4, wf, bf, out);
}

// Round 2
// 499.841 us; speedup vs baseline: 2.4515x; 2.4515x over previous
//
#include <hip/hip_runtime.h>
#include <stdint.h>

constexpr int NB = 128; // batch

// ---------------- weight sign packing ----------------
__global__ void pack_weights_kernel(const float* __restrict__ w, uint32_t* __restrict__ out,
                                    int OC, int ICW)
{
    int idx = blockIdx.x * blockDim.x + threadIdx.x;
    int total = OC * 9 * ICW;
    if (idx >= total) return;
    int iw = idx % ICW;
    int t  = (idx / ICW) % 9;
    int oc = idx / (9 * ICW);
    int IC = ICW * 32;
    uint32_t word = 0;
    for (int b = 0; b < 32; ++b) {
        float wv = w[(size_t)(oc * IC + (iw * 32 + b)) * 9 + t];
        word |= (wv > 0.f ? 1u : 0u) << b;
    }
    out[idx] = word;
}

// ---------------- stage 1: full-precision conv 1->32 ----------------
__device__ __forceinline__ void conv1_load9(const float* __restrict__ x, int p, float* xv)
{
    int n = p >> 14;
    int y = (p >> 7) & 127;
    int c = p & 127;
    const float* xn = x + (size_t)n * 16384;
    #pragma unroll
    for (int ky = 0; ky < 3; ++ky)
    #pragma unroll
    for (int kx = 0; kx < 3; ++kx) {
        int yy = y + ky - 1, cc = c + kx - 1;
        float v = 0.f;
        if (yy >= 0 && yy < 128 && cc >= 0 && cc < 128) v = xn[yy * 128 + cc];
        xv[ky * 3 + kx] = v;
    }
}

__global__ __launch_bounds__(256) void conv1_stats_kernel(
    const float* __restrict__ x, const float* __restrict__ w1, const float* __restrict__ b1,
    float* __restrict__ partials)
{
    __shared__ float wl[320];
    __shared__ float wbuf[4][64];
    int tid = threadIdx.x;
    for (int i = tid; i < 320; i += 256) wl[i] = (i < 288) ? w1[i] : b1[i - 288];
    __syncthreads();

    float xv[4][9];
    int base = blockIdx.x * 256 + tid;
    #pragma unroll
    for (int i = 0; i < 4; ++i) conv1_load9(x, base + i * 524288, xv[i]);

    float sum[32], sq[32];
    #pragma unroll
    for (int oc = 0; oc < 32; ++oc) {
        float w[9];
        #pragma unroll
        for (int t = 0; t < 9; ++t) w[t] = wl[oc * 9 + t];
        float b = wl[288 + oc];
        float s = 0.f, s2 = 0.f;
        #pragma unroll
        for (int i = 0; i < 4; ++i) {
            float a = b;
            #pragma unroll
            for (int t = 0; t < 9; ++t) a = fmaf(xv[i][t], w[t], a);
            s += a; s2 = fmaf(a, a, s2);
        }
        sum[oc] = s; sq[oc] = s2;
    }
    #pragma unroll
    for (int oc = 0; oc < 32; ++oc) {
        float s = sum[oc], s2 = sq[oc];
        #pragma unroll
        for (int off = 32; off >= 1; off >>= 1) {
            s  += __shfl_xor(s,  off, 64);
            s2 += __shfl_xor(s2, off, 64);
        }
        sum[oc] = s; sq[oc] = s2;
    }
    int lane = tid & 63, wv = tid >> 6;
    if (lane == 0) {
        #pragma unroll
        for (int oc = 0; oc < 32; ++oc) { wbuf[wv][oc] = sum[oc]; wbuf[wv][32 + oc] = sq[oc]; }
    }
    __syncthreads();
    if (tid < 64)
        partials[blockIdx.x * 64 + tid] = wbuf[0][tid] + wbuf[1][tid] + wbuf[2][tid] + wbuf[3][tid];
}

__global__ __launch_bounds__(256) void conv1_pack_kernel(
    const float* __restrict__ x, const float* __restrict__ w1, const float* __restrict__ b1,
    const float* __restrict__ ss, uint32_t* __restrict__ s1)
{
    __shared__ float wl[384];
    int tid = threadIdx.x;
    for (int i = tid; i < 384; i += 256)
        wl[i] = (i < 288) ? w1[i] : ((i < 320) ? b1[i - 288] : ss[i - 320]);
    __syncthreads();

    float xv[4][9];
    int base = blockIdx.x * 256 + tid;
    #pragma unroll
    for (int i = 0; i < 4; ++i) conv1_load9(x, base + i * 524288, xv[i]);

    uint32_t word[4] = {0, 0, 0, 0};
    #pragma unroll
    for (int oc = 0; oc < 32; ++oc) {
        float w[9];
        #pragma unroll
        for (int t = 0; t < 9; ++t) w[t] = wl[oc * 9 + t];
        float b = wl[288 + oc];
        float A = wl[320 + oc], B = wl[352 + oc];
        #pragma unroll
        for (int i = 0; i < 4; ++i) {
            float a = b;
            #pragma unroll
            for (int t = 0; t < 9; ++t) a = fmaf(xv[i][t], w[t], a);
            float v = fmaf(A, a, B);
            word[i] |= (v > 0.f ? 1u : 0u) << oc;
        }
    }
    #pragma unroll
    for (int i = 0; i < 4; ++i) s1[base + i * 524288] = word[i];
}

// ---------------- parallel deterministic reduction of partials ----------------
// one block per channel-stat: dsums[ch] = sum_i partials[i*(2*OC)+ch]
template<int OC>
__global__ __launch_bounds__(256) void reduce_partials_kernel(
    const float* __restrict__ partials, int nblk, double* __restrict__ dsums)
{
    __shared__ double wsum[4];
    int ch = blockIdx.x;          // 0 .. 2*OC-1
    int tid = threadIdx.x;
    double a = 0.0;
    for (int i = tid; i < nblk; i += 256)
        a += (double)partials[(size_t)i * (2 * OC) + ch];
    #pragma unroll
    for (int off = 32; off >= 1; off >>= 1)
        a += __shfl_xor(a, off, 64);
    if ((tid & 63) == 0) wsum[tid >> 6] = a;
    __syncthreads();
    if (tid == 0)
        dsums[ch] = (wsum[0] + wsum[1]) + (wsum[2] + wsum[3]);
}

template<int OC>
__global__ void compute_ss_kernel(const double* __restrict__ dsums,
                                  const float* __restrict__ gamma, const float* __restrict__ beta,
                                  float inv_n, float* __restrict__ ss)
{
    int tid = threadIdx.x;
    if (tid >= OC) return;
    float mu  = (float)dsums[tid] * inv_n;
    float ex2 = (float)dsums[OC + tid] * inv_n;
    float var = ex2 - mu * mu;
    float rs  = 1.f / sqrtf(var + 1e-5f);
    float A = gamma[tid] * rs;
    ss[tid] = A;
    ss[OC + tid] = beta[tid] - mu * A;
}

// ---------------- binary conv (xnor-popcount) + 2x2 maxpool ----------------
template<int OC, int W, int P, int MODE, int G>
__global__ __launch_bounds__(256) void binconv_pool_kernel(
    const uint32_t* __restrict__ sin, const uint32_t* __restrict__ wp,
    const float* __restrict__ alpha, const float* __restrict__ ss,
    float* __restrict__ partials, void* __restrict__ sout)
{
    constexpr int PW = W / 2;
    constexpr int TOTAL = NB * PW * PW;
    constexpr int STRIDE = TOTAL / P;
    static_assert(TOTAL % (256 * P) == 0, "grid divisibility");
    static_assert(OC % G == 0, "group divisibility");

    __shared__ uint32_t wl[OC * 9];
    __shared__ float ssl[2 * OC];
    __shared__ float wbuf[4][2 * OC];

    int tid = threadIdx.x;
    for (int i = tid; i < OC * 9; i += 256) wl[i] = wp[i];
    if constexpr (MODE == 1) { if (tid < 2 * OC) ssl[tid] = ss[tid]; }
    __syncthreads();
    float alp = alpha[0];
    int base = blockIdx.x * 256 + tid;

    uint32_t xw[P][16];
    uint32_t wm[P][16];
    int cnt[P][4];
    int pidx[P];
    #pragma unroll
    for (int i = 0; i < P; ++i) {
        int p = base + i * STRIDE;
        pidx[i] = p;
        int n = p / (PW * PW);
        int rem = p % (PW * PW);
        int py = rem / PW, px = rem % PW;
        int r0 = 2 * py - 1, c0 = 2 * px - 1;
        const uint32_t* sp = sin + (size_t)n * W * W;
        #pragma unroll
        for (int a = 0; a < 4; ++a) {
            int r = r0 + a;
            bool rv = (r >= 0) & (r < W);
            #pragma unroll
            for (int b = 0; b < 4; ++b) {
                int c = c0 + b;
                bool v = rv & (c >= 0) & (c < W);
                wm[i][a * 4 + b] = v ? 0xFFFFFFFFu : 0u;
                xw[i][a * 4 + b] = v ? sp[r * W + c] : 0u;
            }
        }
        #pragma unroll
        for (int a2 = 0; a2 < 2; ++a2)
        #pragma unroll
        for (int b2 = 0; b2 < 2; ++b2) {
            int cc = 0;
            #pragma unroll
            for (int ky = 0; ky < 3; ++ky)
            #pragma unroll
            for (int kx = 0; kx < 3; ++kx)
                cc += (int)(wm[i][(a2 + ky) * 4 + (b2 + kx)] & 1u);
            cnt[i][a2 * 2 + b2] = cc * 32;
        }
    }

    uint64_t word[P];
    #pragma unroll
    for (int i = 0; i < P; ++i) word[i] = 0;

    for (int g = 0; g < OC / G; ++g) {
        float s[G], s2[G];
        #pragma unroll
        for (int j = 0; j < G; ++j) { s[j] = 0.f; s2[j] = 0.f; }

        #pragma unroll
        for (int j = 0; j < G; ++j) {
            int oc = g * G + j;
            uint32_t w9[9];
            #pragma unroll
            for (int t = 0; t < 9; ++t) w9[t] = wl[oc * 9 + t];
            #pragma unroll
            for (int i = 0; i < P; ++i) {
                float m = -3.4e38f;
                #pragma unroll
                for (int a2 = 0; a2 < 2; ++a2)
                #pragma unroll
                for (int b2 = 0; b2 < 2; ++b2) {
                    int pop = 0;
                    #pragma unroll
                    for (int ky = 0; ky < 3; ++ky)
                    #pragma unroll
                    for (int kx = 0; kx < 3; ++kx) {
                        int idx = (a2 + ky) * 4 + (b2 + kx);
                        pop += __popc((xw[i][idx] ^ w9[ky * 3 + kx]) & wm[i][idx]);
                    }
                    float v = alp * (float)(cnt[i][a2 * 2 + b2] - 2 * pop);
                    m = fmaxf(m, v);
                }
                if constexpr (MODE == 0) {
                    s[j] += m; s2[j] = fmaf(m, m, s2[j]);
                } else {
                    float vv = fmaf(ssl[oc], m, ssl[OC + oc]);
                    word[i] |= (vv > 0.f ? 1ull : 0ull) << oc;
                }
            }
        }
        if constexpr (MODE == 0) {
            int lane = tid & 63, wv = tid >> 6;
            #pragma unroll
            for (int j = 0; j < G; ++j) {
                float a = s[j], b = s2[j];
                #pragma unroll
                for (int off = 32; off >= 1; off >>= 1) {
                    a += __shfl_xor(a, off, 64);
                    b += __shfl_xor(b, off, 64);
                }
                if (lane == 0) { wbuf[wv][g * G + j] = a; wbuf[wv][OC + g * G + j] = b; }
            }
        }
    }

    if constexpr (MODE == 1) {
        #pragma unroll
        for (int i = 0; i < P; ++i) {
            if constexpr (OC == 32) ((uint32_t*)sout)[pidx[i]] = (uint32_t)word[i];
            else                    ((uint64_t*)sout)[pidx[i]] = word[i];
        }
    } else {
        __syncthreads();
        if (tid < 2 * OC)
            partials[blockIdx.x * (2 * OC) + tid] =
                wbuf[0][tid] + wbuf[1][tid] + wbuf[2][tid] + wbuf[3][tid];
    }
}

// ---------------- stage 4: binary conv 64->128 + global mean ----------------
__global__ __launch_bounds__(256) void conv4_mean_kernel(
    const uint64_t* __restrict__ s3, const uint64_t* __restrict__ wp4,
    const float* __restrict__ alpha4, float* __restrict__ mean4)
{
    __shared__ uint64_t xt[1024];
    __shared__ uint64_t wl[1152];
    __shared__ float red[256];
    int n = blockIdx.x, tid = threadIdx.x;
    for (int i = tid; i < 1024; i += 256) xt[i] = s3[n * 1024 + i];
    for (int i = tid; i < 1152; i += 256) wl[i] = wp4[i];
    __syncthreads();
    int oc = tid & 127, h = tid >> 7;
    uint64_t wr[9];
    #pragma unroll
    for (int t = 0; t < 9; ++t) wr[t] = wl[oc * 9 + t];
    int acc = 0;
    for (int y = h * 16; y < h * 16 + 16; ++y) {
        for (int x = 0; x < 32; ++x) {
            int pop = 0, c = 0;
            #pragma unroll
            for (int ky = 0; ky < 3; ++ky) {
                int yy = y + ky - 1;
                if (yy < 0 || yy >= 32) continue;
                #pragma unroll
                for (int kx = 0; kx < 3; ++kx) {
                    int xx = x + kx - 1;
                    if (xx < 0 || xx >= 32) continue;
                    pop += __popcll(xt[yy * 32 + xx] ^ wr[ky * 3 + kx]);
                    c += 64;
                }
            }
            acc += c - 2 * pop;
        }
    }
    red[tid] = (float)acc;
    __syncthreads();
    if (tid < 128)
        mean4[n * 128 + tid] = (red[tid] + red[tid + 128]) * alpha4[0] * (1.f / 1024.f);
}

// ---------------- classifier ----------------
__global__ void linear_kernel(const float* __restrict__ mean4, const float* __restrict__ wf,
                              const float* __restrict__ bf, float* __restrict__ out)
{
    int t = blockIdx.x * blockDim.x + threadIdx.x;
    if (t >= 1280) return;
    int n = t / 10, k = t % 10;
    const float* m = mean4 + n * 128;
    const float* w = wf + k * 128;
    float a = bf[k];
    #pragma unroll 4
    for (int i = 0; i < 128; ++i) a = fmaf(m[i], w[i], a);
    out[t] = a;
}

extern "C" void kernel_launch(void* const* d_in, const int* in_sizes, int n_in,
                              void* d_out, int out_size, void* d_ws, size_t ws_size,
                              hipStream_t stream)
{
    const float* x   = (const float*)d_in[0];
    const float* w1  = (const float*)d_in[1];
    const float* b1  = (const float*)d_in[2];
    const float* g1  = (const float*)d_in[3];
    const float* be1 = (const float*)d_in[4];
    const float* w2  = (const float*)d_in[5];
    const float* a2  = (const float*)d_in[6];
    const float* g2  = (const float*)d_in[7];
    const float* be2 = (const float*)d_in[8];
    const float* w3  = (const float*)d_in[9];
    const float* a3  = (const float*)d_in[10];
    const float* g3  = (const float*)d_in[11];
    const float* be3 = (const float*)d_in[12];
    const float* w4  = (const float*)d_in[13];
    const float* a4  = (const float*)d_in[14];
    const float* wf  = (const float*)d_in[15];
    const float* bf  = (const float*)d_in[16];
    float* out = (float*)d_out;

    uint8_t* ws = (uint8_t*)d_ws;
    size_t off = 0;
    auto alloc = [&](size_t bytes) -> void* {
        void* p = ws + off;
        off += (bytes + 255) & ~(size_t)255;
        return p;
    };
    uint32_t* wp2 = (uint32_t*)alloc(288 * 4);
    uint32_t* wp3 = (uint32_t*)alloc(576 * 4);
    uint32_t* wp4 = (uint32_t*)alloc(2304 * 4);
    float* ss1 = (float*)alloc(64 * 4);
    float* ss2 = (float*)alloc(64 * 4);
    float* ss3 = (float*)alloc(128 * 4);
    double* dsums = (double*)alloc(128 * 8);
    uint32_t* s1 = (uint32_t*)alloc((size_t)128 * 128 * 128 * 4);
    uint32_t* s2 = (uint32_t*)alloc((size_t)128 * 64 * 64 * 4);
    uint64_t* s3 = (uint64_t*)alloc((size_t)128 * 32 * 32 * 8);
    float* mean4 = (float*)alloc((size_t)128 * 128 * 4);
    float* partials = (float*)alloc((size_t)2048 * 64 * 4);

    // pack weight signs
    pack_weights_kernel<<<2, 256, 0, stream>>>(w2, wp2, 32, 1);
    pack_weights_kernel<<<3, 256, 0, stream>>>(w3, wp3, 64, 1);
    pack_weights_kernel<<<9, 256, 0, stream>>>(w4, wp4, 128, 2);

    // stage 1: fp conv -> BN stats -> sign+pack
    conv1_stats_kernel<<<2048, 256, 0, stream>>>(x, w1, b1, partials);
    reduce_partials_kernel<32><<<64, 256, 0, stream>>>(partials, 2048, dsums);
    compute_ss_kernel<32><<<1, 32, 0, stream>>>(dsums, g1, be1, 1.f / 2097152.f, ss1);
    conv1_pack_kernel<<<2048, 256, 0, stream>>>(x, w1, b1, ss1, s1);

    // stage 2: binconv 32->32 @128 + pool -> BN -> sign+pack
    binconv_pool_kernel<32, 128, 2, 0, 4><<<1024, 256, 0, stream>>>(s1, wp2, a2, nullptr, partials, nullptr);
    reduce_partials_kernel<32><<<64, 256, 0, stream>>>(partials, 1024, dsums);
    compute_ss_kernel<32><<<1, 32, 0, stream>>>(dsums, g2, be2, 1.f / 524288.f, ss2);
    binconv_pool_kernel<32, 128, 2, 1, 4><<<1024, 256, 0, stream>>>(s1, wp2, a2, ss2, nullptr, (void*)s2);

    // stage 3: binconv 32->64 @64 + pool -> BN -> sign+pack
    binconv_pool_kernel<64, 64, 2, 0, 4><<<256, 256, 0, stream>>>(s2, wp3, a3, nullptr, partials, nullptr);
    reduce_partials_kernel<64><<<128, 256, 0, stream>>>(partials, 256, dsums);
    compute_ss_kernel<64><<<1, 64, 0, stream>>>(dsums, g3, be3, 1.f / 131072.f, ss3);
    binconv_pool_kernel<64, 64, 2, 1, 4><<<256, 256, 0, stream>>>(s2, wp3, a3, ss3, nullptr, (void*)s3);

    // stage 4: binconv 64->128 @32 + global mean, then classifier
    conv4_mean_kernel<<<128, 256, 0, stream>>>(s3, (const uint64_t*)wp4, a4, mean4);
    linear_kernel<<<5, 256, 0, stream>>>(mean4, wf, bf, out);
}

// Round 3
// 404.750 us; speedup vs baseline: 3.0274x; 1.2349x over previous
//
#include <hip/hip_runtime.h>
#include <stdint.h>

constexpr int NB = 128; // batch

// ---------------- weight sign packing ----------------
__global__ void pack_weights_kernel(const float* __restrict__ w, uint32_t* __restrict__ out,
                                    int OC, int ICW)
{
    int idx = blockIdx.x * blockDim.x + threadIdx.x;
    int total = OC * 9 * ICW;
    if (idx >= total) return;
    int iw = idx % ICW;
    int t  = (idx / ICW) % 9;
    int oc = idx / (9 * ICW);
    int IC = ICW * 32;
    uint32_t word = 0;
    for (int b = 0; b < 32; ++b) {
        float wv = w[(size_t)(oc * IC + (iw * 32 + b)) * 9 + t];
        word |= (wv > 0.f ? 1u : 0u) << b;
    }
    out[idx] = word;
}

// ---------------- stage 1: full-precision conv 1->32 ----------------
__device__ __forceinline__ void conv1_load9(const float* __restrict__ x, int p, float* xv)
{
    int n = p >> 14;
    int y = (p >> 7) & 127;
    int c = p & 127;
    const float* xn = x + (size_t)n * 16384;
    #pragma unroll
    for (int ky = 0; ky < 3; ++ky)
    #pragma unroll
    for (int kx = 0; kx < 3; ++kx) {
        int yy = y + ky - 1, cc = c + kx - 1;
        float v = 0.f;
        if (yy >= 0 && yy < 128 && cc >= 0 && cc < 128) v = xn[yy * 128 + cc];
        xv[ky * 3 + kx] = v;
    }
}

__global__ __launch_bounds__(256) void conv1_stats_kernel(
    const float* __restrict__ x, const float* __restrict__ w1, const float* __restrict__ b1,
    float* __restrict__ partials)
{
    __shared__ float wl[320];
    __shared__ float wbuf[4][64];
    int tid = threadIdx.x;
    for (int i = tid; i < 320; i += 256) wl[i] = (i < 288) ? w1[i] : b1[i - 288];
    __syncthreads();

    float xv[4][9];
    int base = blockIdx.x * 256 + tid;
    #pragma unroll
    for (int i = 0; i < 4; ++i) conv1_load9(x, base + i * 524288, xv[i]);

    float sum[32], sq[32];
    #pragma unroll
    for (int oc = 0; oc < 32; ++oc) {
        float w[9];
        #pragma unroll
        for (int t = 0; t < 9; ++t) w[t] = wl[oc * 9 + t];
        float b = wl[288 + oc];
        float s = 0.f, s2 = 0.f;
        #pragma unroll
        for (int i = 0; i < 4; ++i) {
            float a = b;
            #pragma unroll
            for (int t = 0; t < 9; ++t) a = fmaf(xv[i][t], w[t], a);
            s += a; s2 = fmaf(a, a, s2);
        }
        sum[oc] = s; sq[oc] = s2;
    }
    #pragma unroll
    for (int oc = 0; oc < 32; ++oc) {
        float s = sum[oc], s2 = sq[oc];
        #pragma unroll
        for (int off = 32; off >= 1; off >>= 1) {
            s  += __shfl_xor(s,  off, 64);
            s2 += __shfl_xor(s2, off, 64);
        }
        sum[oc] = s; sq[oc] = s2;
    }
    int lane = tid & 63, wv = tid >> 6;
    if (lane == 0) {
        #pragma unroll
        for (int oc = 0; oc < 32; ++oc) { wbuf[wv][oc] = sum[oc]; wbuf[wv][32 + oc] = sq[oc]; }
    }
    __syncthreads();
    if (tid < 64)
        partials[blockIdx.x * 64 + tid] = wbuf[0][tid] + wbuf[1][tid] + wbuf[2][tid] + wbuf[3][tid];
}

__global__ __launch_bounds__(256) void conv1_pack_kernel(
    const float* __restrict__ x, const float* __restrict__ w1, const float* __restrict__ b1,
    const float* __restrict__ ss, uint32_t* __restrict__ s1)
{
    __shared__ float wl[384];
    int tid = threadIdx.x;
    for (int i = tid; i < 384; i += 256)
        wl[i] = (i < 288) ? w1[i] : ((i < 320) ? b1[i - 288] : ss[i - 320]);
    __syncthreads();

    float xv[4][9];
    int base = blockIdx.x * 256 + tid;
    #pragma unroll
    for (int i = 0; i < 4; ++i) conv1_load9(x, base + i * 524288, xv[i]);

    uint32_t word[4] = {0, 0, 0, 0};
    #pragma unroll
    for (int oc = 0; oc < 32; ++oc) {
        float w[9];
        #pragma unroll
        for (int t = 0; t < 9; ++t) w[t] = wl[oc * 9 + t];
        float b = wl[288 + oc];
        float A = wl[320 + oc], B = wl[352 + oc];
        #pragma unroll
        for (int i = 0; i < 4; ++i) {
            float a = b;
            #pragma unroll
            for (int t = 0; t < 9; ++t) a = fmaf(xv[i][t], w[t], a);
            float v = fmaf(A, a, B);
            word[i] |= (v > 0.f ? 1u : 0u) << oc;
        }
    }
    #pragma unroll
    for (int i = 0; i < 4; ++i) s1[base + i * 524288] = word[i];
}

// ---------------- parallel deterministic reduction of partials ----------------
template<int OC>
__global__ __launch_bounds__(256) void reduce_partials_kernel(
    const float* __restrict__ partials, int nblk, double* __restrict__ dsums)
{
    __shared__ double wsum[4];
    int ch = blockIdx.x;          // 0 .. 2*OC-1
    int tid = threadIdx.x;
    double a = 0.0;
    for (int i = tid; i < nblk; i += 256)
        a += (double)partials[(size_t)i * (2 * OC) + ch];
    #pragma unroll
    for (int off = 32; off >= 1; off >>= 1)
        a += __shfl_xor(a, off, 64);
    if ((tid & 63) == 0) wsum[tid >> 6] = a;
    __syncthreads();
    if (tid == 0)
        dsums[ch] = (wsum[0] + wsum[1]) + (wsum[2] + wsum[3]);
}

template<int OC>
__global__ void compute_ss_kernel(const double* __restrict__ dsums,
                                  const float* __restrict__ gamma, const float* __restrict__ beta,
                                  float inv_n, float* __restrict__ ss)
{
    int tid = threadIdx.x;
    if (tid >= OC) return;
    float mu  = (float)dsums[tid] * inv_n;
    float ex2 = (float)dsums[OC + tid] * inv_n;
    float var = ex2 - mu * mu;
    float rs  = 1.f / sqrtf(var + 1e-5f);
    float A = gamma[tid] * rs;
    ss[tid] = A;
    ss[OC + tid] = beta[tid] - mu * A;
}

// ---------------- binary conv (xnor-popcount) + 2x2 maxpool ----------------
template<int OC, int W, int P, int MODE, int G>
__global__ __launch_bounds__(256) void binconv_pool_kernel(
    const uint32_t* __restrict__ sin, const uint32_t* __restrict__ wp,
    const float* __restrict__ alpha, const float* __restrict__ ss,
    float* __restrict__ partials, void* __restrict__ sout)
{
    constexpr int PW = W / 2;
    constexpr int TOTAL = NB * PW * PW;
    constexpr int STRIDE = TOTAL / P;
    static_assert(TOTAL % (256 * P) == 0, "grid divisibility");
    static_assert(OC % G == 0, "group divisibility");

    __shared__ uint32_t wl[OC * 9];
    __shared__ float ssl[2 * OC];
    __shared__ float wbuf[4][2 * OC];

    int tid = threadIdx.x;
    for (int i = tid; i < OC * 9; i += 256) wl[i] = wp[i];
    if constexpr (MODE == 1) { if (tid < 2 * OC) ssl[tid] = ss[tid]; }
    __syncthreads();
    float alp = alpha[0];
    int base = blockIdx.x * 256 + tid;

    uint32_t xw[P][16];
    uint32_t wm[P][16];
    int cnt[P][4];
    int pidx[P];
    #pragma unroll
    for (int i = 0; i < P; ++i) {
        int p = base + i * STRIDE;
        pidx[i] = p;
        int n = p / (PW * PW);
        int rem = p % (PW * PW);
        int py = rem / PW, px = rem % PW;
        int r0 = 2 * py - 1, c0 = 2 * px - 1;
        const uint32_t* sp = sin + (size_t)n * W * W;
        #pragma unroll
        for (int a = 0; a < 4; ++a) {
            int r = r0 + a;
            bool rv = (r >= 0) & (r < W);
            #pragma unroll
            for (int b = 0; b < 4; ++b) {
                int c = c0 + b;
                bool v = rv & (c >= 0) & (c < W);
                wm[i][a * 4 + b] = v ? 0xFFFFFFFFu : 0u;
                xw[i][a * 4 + b] = v ? sp[r * W + c] : 0u;
            }
        }
        #pragma unroll
        for (int a2 = 0; a2 < 2; ++a2)
        #pragma unroll
        for (int b2 = 0; b2 < 2; ++b2) {
            int cc = 0;
            #pragma unroll
            for (int ky = 0; ky < 3; ++ky)
            #pragma unroll
            for (int kx = 0; kx < 3; ++kx)
                cc += (int)(wm[i][(a2 + ky) * 4 + (b2 + kx)] & 1u);
            cnt[i][a2 * 2 + b2] = cc * 32;
        }
    }

    uint64_t word[P];
    #pragma unroll
    for (int i = 0; i < P; ++i) word[i] = 0;

    for (int g = 0; g < OC / G; ++g) {
        float s[G], s2[G];
        #pragma unroll
        for (int j = 0; j < G; ++j) { s[j] = 0.f; s2[j] = 0.f; }

        #pragma unroll
        for (int j = 0; j < G; ++j) {
            int oc = g * G + j;
            uint32_t w9[9];
            #pragma unroll
            for (int t = 0; t < 9; ++t) w9[t] = wl[oc * 9 + t];
            #pragma unroll
            for (int i = 0; i < P; ++i) {
                float m = -3.4e38f;
                #pragma unroll
                for (int a2 = 0; a2 < 2; ++a2)
                #pragma unroll
                for (int b2 = 0; b2 < 2; ++b2) {
                    int pop = 0;
                    #pragma unroll
                    for (int ky = 0; ky < 3; ++ky)
                    #pragma unroll
                    for (int kx = 0; kx < 3; ++kx) {
                        int idx = (a2 + ky) * 4 + (b2 + kx);
                        pop += __popc((xw[i][idx] ^ w9[ky * 3 + kx]) & wm[i][idx]);
                    }
                    float v = alp * (float)(cnt[i][a2 * 2 + b2] - 2 * pop);
                    m = fmaxf(m, v);
                }
                if constexpr (MODE == 0) {
                    s[j] += m; s2[j] = fmaf(m, m, s2[j]);
                } else {
                    float vv = fmaf(ssl[oc], m, ssl[OC + oc]);
                    word[i] |= (vv > 0.f ? 1ull : 0ull) << oc;
                }
            }
        }
        if constexpr (MODE == 0) {
            int lane = tid & 63, wv = tid >> 6;
            #pragma unroll
            for (int j = 0; j < G; ++j) {
                float a = s[j], b = s2[j];
                #pragma unroll
                for (int off = 32; off >= 1; off >>= 1) {
                    a += __shfl_xor(a, off, 64);
                    b += __shfl_xor(b, off, 64);
                }
                if (lane == 0) { wbuf[wv][g * G + j] = a; wbuf[wv][OC + g * G + j] = b; }
            }
        }
    }

    if constexpr (MODE == 1) {
        #pragma unroll
        for (int i = 0; i < P; ++i) {
            if constexpr (OC == 32) ((uint32_t*)sout)[pidx[i]] = (uint32_t)word[i];
            else                    ((uint64_t*)sout)[pidx[i]] = word[i];
        }
    } else {
        __syncthreads();
        if (tid < 2 * OC)
            partials[blockIdx.x * (2 * OC) + tid] =
                wbuf[0][tid] + wbuf[1][tid] + wbuf[2][tid] + wbuf[3][tid];
    }
}

// ---------------- stage 4: binary conv 64->128, slab partials ----------------
// grid = NB * 8 blocks; block b: image n = b>>3, row slab s = b&7 (rows 4s..4s+3)
__global__ __launch_bounds__(256) void conv4_partial_kernel(
    const uint64_t* __restrict__ s3, const uint64_t* __restrict__ wp4,
    float* __restrict__ p4)
{
    __shared__ uint64_t xt[192];    // 6 rows x 32 cols (halo)
    __shared__ uint64_t wl[1152];
    __shared__ float red[256];
    int b = blockIdx.x;
    int n = b >> 3, s = b & 7;
    int tid = threadIdx.x;
    for (int i = tid; i < 192; i += 256) {
        int row = 4 * s - 1 + (i >> 5);
        int col = i & 31;
        xt[i] = (row >= 0 && row < 32) ? s3[(size_t)n * 1024 + row * 32 + col] : 0ull;
    }
    for (int i = tid; i < 1152; i += 256) wl[i] = wp4[i];
    __syncthreads();
    int oc = tid & 127, h = tid >> 7;
    uint64_t wr[9];
    #pragma unroll
    for (int t = 0; t < 9; ++t) wr[t] = wl[oc * 9 + t];
    int acc = 0;
    #pragma unroll
    for (int ry = 0; ry < 2; ++ry) {
        int lry = 2 * h + ry;           // local row 0..3
        int y = 4 * s + lry;            // global row
        for (int x = 0; x < 32; ++x) {
            int pop = 0, c = 0;
            #pragma unroll
            for (int ky = 0; ky < 3; ++ky) {
                int yy = y + ky - 1;
                if (yy < 0 || yy >= 32) continue;
                int lrow = lry + ky;    // 0..5 in halo space
                #pragma unroll
                for (int kx = 0; kx < 3; ++kx) {
                    int xx = x + kx - 1;
                    if (xx < 0 || xx >= 32) continue;
                    pop += __popcll(xt[lrow * 32 + xx] ^ wr[ky * 3 + kx]);
                    c += 64;
                }
            }
            acc += c - 2 * pop;
        }
    }
    red[tid] = (float)acc;
    __syncthreads();
    if (tid < 128)
        p4[(size_t)b * 128 + tid] = red[tid] + red[tid + 128];
}

// mean over 8 slabs -> mean4[n*128+oc]
__global__ void mean4_kernel(const float* __restrict__ p4, const float* __restrict__ alpha4,
                             float* __restrict__ mean4)
{
    int t = blockIdx.x * blockDim.x + threadIdx.x;
    if (t >= NB * 128) return;
    int n = t >> 7, oc = t & 127;
    float a = 0.f;
    #pragma unroll
    for (int s = 0; s < 8; ++s)
        a += p4[(size_t)((n * 8 + s) * 128) + oc];
    mean4[t] = a * alpha4[0] * (1.f / 1024.f);
}

// ---------------- classifier ----------------
__global__ void linear_kernel(const float* __restrict__ mean4, const float* __restrict__ wf,
                              const float* __restrict__ bf, float* __restrict__ out)
{
    int t = blockIdx.x * blockDim.x + threadIdx.x;
    if (t >= 1280) return;
    int n = t / 10, k = t % 10;
    const float* m = mean4 + n * 128;
    const float* w = wf + k * 128;
    float a = bf[k];
    #pragma unroll 4
    for (int i = 0; i < 128; ++i) a = fmaf(m[i], w[i], a);
    out[t] = a;
}

extern "C" void kernel_launch(void* const* d_in, const int* in_sizes, int n_in,
                              void* d_out, int out_size, void* d_ws, size_t ws_size,
                              hipStream_t stream)
{
    const float* x   = (const float*)d_in[0];
    const float* w1  = (const float*)d_in[1];
    const float* b1  = (const float*)d_in[2];
    const float* g1  = (const float*)d_in[3];
    const float* be1 = (const float*)d_in[4];
    const float* w2  = (const float*)d_in[5];
    const float* a2  = (const float*)d_in[6];
    const float* g2  = (const float*)d_in[7];
    const float* be2 = (const float*)d_in[8];
    const float* w3  = (const float*)d_in[9];
    const float* a3  = (const float*)d_in[10];
    const float* g3  = (const float*)d_in[11];
    const float* be3 = (const float*)d_in[12];
    const float* w4  = (const float*)d_in[13];
    const float* a4  = (const float*)d_in[14];
    const float* wf  = (const float*)d_in[15];
    const float* bf  = (const float*)d_in[16];
    float* out = (float*)d_out;

    uint8_t* ws = (uint8_t*)d_ws;
    size_t off = 0;
    auto alloc = [&](size_t bytes) -> void* {
        void* p = ws + off;
        off += (bytes + 255) & ~(size_t)255;
        return p;
    };
    uint32_t* wp2 = (uint32_t*)alloc(288 * 4);
    uint32_t* wp3 = (uint32_t*)alloc(576 * 4);
    uint32_t* wp4 = (uint32_t*)alloc(2304 * 4);
    float* ss1 = (float*)alloc(64 * 4);
    float* ss2 = (float*)alloc(64 * 4);
    float* ss3 = (float*)alloc(128 * 4);
    double* dsums = (double*)alloc(128 * 8);
    uint32_t* s1 = (uint32_t*)alloc((size_t)128 * 128 * 128 * 4);
    uint32_t* s2 = (uint32_t*)alloc((size_t)128 * 64 * 64 * 4);
    uint64_t* s3 = (uint64_t*)alloc((size_t)128 * 32 * 32 * 8);
    float* mean4 = (float*)alloc((size_t)128 * 128 * 4);
    float* p4    = (float*)alloc((size_t)1024 * 128 * 4);
    float* partials = (float*)alloc((size_t)2048 * 64 * 4);

    // pack weight signs
    pack_weights_kernel<<<2, 256, 0, stream>>>(w2, wp2, 32, 1);
    pack_weights_kernel<<<3, 256, 0, stream>>>(w3, wp3, 64, 1);
    pack_weights_kernel<<<9, 256, 0, stream>>>(w4, wp4, 128, 2);

    // stage 1: fp conv -> BN stats -> sign+pack
    conv1_stats_kernel<<<2048, 256, 0, stream>>>(x, w1, b1, partials);
    reduce_partials_kernel<32><<<64, 256, 0, stream>>>(partials, 2048, dsums);
    compute_ss_kernel<32><<<1, 32, 0, stream>>>(dsums, g1, be1, 1.f / 2097152.f, ss1);
    conv1_pack_kernel<<<2048, 256, 0, stream>>>(x, w1, b1, ss1, s1);

    // stage 2: binconv 32->32 @128 + pool -> BN -> sign+pack  (P=1, 2048 blocks)
    binconv_pool_kernel<32, 128, 1, 0, 4><<<2048, 256, 0, stream>>>(s1, wp2, a2, nullptr, partials, nullptr);
    reduce_partials_kernel<32><<<64, 256, 0, stream>>>(partials, 2048, dsums);
    compute_ss_kernel<32><<<1, 32, 0, stream>>>(dsums, g2, be2, 1.f / 524288.f, ss2);
    binconv_pool_kernel<32, 128, 1, 1, 4><<<2048, 256, 0, stream>>>(s1, wp2, a2, ss2, nullptr, (void*)s2);

    // stage 3: binconv 32->64 @64 + pool -> BN -> sign+pack  (P=1, 512 blocks)
    binconv_pool_kernel<64, 64, 1, 0, 4><<<512, 256, 0, stream>>>(s2, wp3, a3, nullptr, partials, nullptr);
    reduce_partials_kernel<64><<<128, 256, 0, stream>>>(partials, 512, dsums);
    compute_ss_kernel<64><<<1, 64, 0, stream>>>(dsums, g3, be3, 1.f / 131072.f, ss3);
    binconv_pool_kernel<64, 64, 1, 1, 4><<<512, 256, 0, stream>>>(s2, wp3, a3, ss3, nullptr, (void*)s3);

    // stage 4: binconv 64->128 @32, slab partials -> mean -> classifier
    conv4_partial_kernel<<<1024, 256, 0, stream>>>(s3, (const uint64_t*)wp4, p4);
    mean4_kernel<<<64, 256, 0, stream>>>(p4, a4, mean4);
    linear_kernel<<<5, 256, 0, stream>>>(mean4, wf, bf, out);
}

// Round 4
// 244.655 us; speedup vs baseline: 5.0084x; 1.6544x over previous
//
#include <hip/hip_runtime.h>
#include <stdint.h>
#include <limits.h>

constexpr int NB = 128; // batch

// ---------------- weight sign packing ----------------
__global__ void pack_weights_kernel(const float* __restrict__ w, uint32_t* __restrict__ out,
                                    int OC, int ICW)
{
    int idx = blockIdx.x * blockDim.x + threadIdx.x;
    int total = OC * 9 * ICW;
    if (idx >= total) return;
    int iw = idx % ICW;
    int t  = (idx / ICW) % 9;
    int oc = idx / (9 * ICW);
    int IC = ICW * 32;
    uint32_t word = 0;
    for (int b = 0; b < 32; ++b) {
        float wv = w[(size_t)(oc * IC + (iw * 32 + b)) * 9 + t];
        word |= (wv > 0.f ? 1u : 0u) << b;
    }
    out[idx] = word;
}

// ---------------- stage 1 helpers ----------------
__device__ __forceinline__ void conv1_load9(const float* __restrict__ x, int p, float* xv)
{
    int n = p >> 14;
    int y = (p >> 7) & 127;
    int c = p & 127;
    const float* xn = x + (size_t)n * 16384;
    #pragma unroll
    for (int ky = 0; ky < 3; ++ky)
    #pragma unroll
    for (int kx = 0; kx < 3; ++kx) {
        int yy = y + ky - 1, cc = c + kx - 1;
        float v = 0.f;
        if (yy >= 0 && yy < 128 && cc >= 0 && cc < 128) v = xn[yy * 128 + cc];
        xv[ky * 3 + kx] = v;
    }
}

// ---------------- stage 1 stats via 9+45 cross-correlation sums ----------------
// grid 512 x 256, 16 pixels/thread. partials[block][64]: 0..8 = S_t, 9..53 = C_{t<=u}
__global__ __launch_bounds__(256) void xcorr_kernel(const float* __restrict__ x,
                                                    float* __restrict__ partials)
{
    __shared__ float wbuf[4][64];
    int tid = threadIdx.x;
    float s[9], c[45];
    #pragma unroll
    for (int t = 0; t < 9; ++t) s[t] = 0.f;
    #pragma unroll
    for (int q = 0; q < 45; ++q) c[q] = 0.f;

    int base = blockIdx.x * 256 + tid;
    #pragma unroll 4
    for (int k = 0; k < 16; ++k) {
        float xv[9];
        conv1_load9(x, base + k * 131072, xv);
        #pragma unroll
        for (int t = 0; t < 9; ++t) {
            s[t] += xv[t];
            #pragma unroll
            for (int u = t; u < 9; ++u) {
                int q = t * (19 - t) / 2 + (u - t);
                c[q] = fmaf(xv[t], xv[u], c[q]);
            }
        }
    }
    #pragma unroll
    for (int t = 0; t < 9; ++t) {
        float a = s[t];
        #pragma unroll
        for (int off = 32; off >= 1; off >>= 1) a += __shfl_xor(a, off, 64);
        s[t] = a;
    }
    #pragma unroll
    for (int q = 0; q < 45; ++q) {
        float a = c[q];
        #pragma unroll
        for (int off = 32; off >= 1; off >>= 1) a += __shfl_xor(a, off, 64);
        c[q] = a;
    }
    int lane = tid & 63, wv = tid >> 6;
    if (lane == 0) {
        #pragma unroll
        for (int t = 0; t < 9; ++t) wbuf[wv][t] = s[t];
        #pragma unroll
        for (int q = 0; q < 45; ++q) wbuf[wv][9 + q] = c[q];
    }
    __syncthreads();
    if (tid < 54)
        partials[blockIdx.x * 64 + tid] =
            (wbuf[0][tid] + wbuf[1][tid]) + (wbuf[2][tid] + wbuf[3][tid]);
}

// stage-1 BN scale/shift from S, C sums (exact math in double)
__global__ void compute_ss1_kernel(const double* __restrict__ dsums,
                                   const float* __restrict__ w1, const float* __restrict__ b1,
                                   const float* __restrict__ g1, const float* __restrict__ be1,
                                   float* __restrict__ ss)
{
    __shared__ double S[9], C[45];
    int tid = threadIdx.x;
    if (tid < 9) S[tid] = dsums[tid];
    else if (tid < 54) C[tid - 9] = dsums[tid];
    __syncthreads();
    if (tid >= 32) return;
    double b = (double)b1[tid];
    double w[9];
    #pragma unroll
    for (int t = 0; t < 9; ++t) w[t] = (double)w1[tid * 9 + t];
    double Sdot = 0.0, Q = 0.0;
    #pragma unroll
    for (int t = 0; t < 9; ++t) {
        Sdot += w[t] * S[t];
        #pragma unroll
        for (int u = t; u < 9; ++u) {
            int q = t * (19 - t) / 2 + (u - t);
            double term = w[t] * w[u] * C[q];
            Q += (u == t) ? term : 2.0 * term;
        }
    }
    const double N = 2097152.0;
    double mu  = Sdot / N + b;
    double ex2 = (Q + 2.0 * b * Sdot) / N + b * b;
    float var = (float)(ex2 - mu * mu);
    float A = g1[tid] * (1.f / sqrtf(var + 1e-5f));
    ss[tid] = A;
    ss[32 + tid] = be1[tid] - (float)mu * A;
}

__global__ __launch_bounds__(256) void conv1_pack_kernel(
    const float* __restrict__ x, const float* __restrict__ w1, const float* __restrict__ b1,
    const float* __restrict__ ss, uint32_t* __restrict__ s1)
{
    __shared__ float wl[384];
    int tid = threadIdx.x;
    for (int i = tid; i < 384; i += 256)
        wl[i] = (i < 288) ? w1[i] : ((i < 320) ? b1[i - 288] : ss[i - 320]);
    __syncthreads();

    float xv[4][9];
    int base = blockIdx.x * 256 + tid;
    #pragma unroll
    for (int i = 0; i < 4; ++i) conv1_load9(x, base + i * 524288, xv[i]);

    uint32_t word[4] = {0, 0, 0, 0};
    #pragma unroll
    for (int oc = 0; oc < 32; ++oc) {
        float w[9];
        #pragma unroll
        for (int t = 0; t < 9; ++t) w[t] = wl[oc * 9 + t];
        float b = wl[288 + oc];
        float A = wl[320 + oc], B = wl[352 + oc];
        #pragma unroll
        for (int i = 0; i < 4; ++i) {
            float a = b;
            #pragma unroll
            for (int t = 0; t < 9; ++t) a = fmaf(xv[i][t], w[t], a);
            float v = fmaf(A, a, B);
            word[i] |= (v > 0.f ? 1u : 0u) << oc;
        }
    }
    #pragma unroll
    for (int i = 0; i < 4; ++i) s1[base + i * 524288] = word[i];
}

// ---------------- parallel deterministic reduction of partials ----------------
template<int CH, int STRIDE>
__global__ __launch_bounds__(256) void reduce_partials_kernel(
    const float* __restrict__ partials, int nblk, double* __restrict__ dsums)
{
    __shared__ double wsum[4];
    int ch = blockIdx.x;          // 0 .. CH-1
    int tid = threadIdx.x;
    double a = 0.0;
    for (int i = tid; i < nblk; i += 256)
        a += (double)partials[(size_t)i * STRIDE + ch];
    #pragma unroll
    for (int off = 32; off >= 1; off >>= 1)
        a += __shfl_xor(a, off, 64);
    if ((tid & 63) == 0) wsum[tid >> 6] = a;
    __syncthreads();
    if (tid == 0)
        dsums[ch] = (wsum[0] + wsum[1]) + (wsum[2] + wsum[3]);
}

template<int OC>
__global__ void compute_ss_kernel(const double* __restrict__ dsums,
                                  const float* __restrict__ gamma, const float* __restrict__ beta,
                                  float inv_n, float* __restrict__ ss)
{
    int tid = threadIdx.x;
    if (tid >= OC) return;
    float mu  = (float)dsums[tid] * inv_n;
    float ex2 = (float)dsums[OC + tid] * inv_n;
    float var = ex2 - mu * mu;
    float rs  = 1.f / sqrtf(var + 1e-5f);
    float A = gamma[tid] * rs;
    ss[tid] = A;
    ss[OC + tid] = beta[tid] - mu * A;
}

// ---------------- binary conv + pool: window load helper ----------------
template<int W>
__device__ __forceinline__ void bc_load_window(const uint32_t* __restrict__ sin, int p,
                                               uint32_t* xw, uint32_t* wm, int* cnt)
{
    constexpr int PW = W / 2;
    int n = p / (PW * PW);
    int rem = p % (PW * PW);
    int py = rem / PW, px = rem % PW;
    int r0 = 2 * py - 1, c0 = 2 * px - 1;
    const uint32_t* sp = sin + (size_t)n * W * W;
    #pragma unroll
    for (int a = 0; a < 4; ++a) {
        int r = r0 + a;
        bool rv = (r >= 0) & (r < W);
        #pragma unroll
        for (int b = 0; b < 4; ++b) {
            int c = c0 + b;
            bool v = rv & (c >= 0) & (c < W);
            wm[a * 4 + b] = v ? 0xFFFFFFFFu : 0u;
            xw[a * 4 + b] = v ? sp[r * W + c] : 0u;
        }
    }
    #pragma unroll
    for (int a2 = 0; a2 < 2; ++a2)
    #pragma unroll
    for (int b2 = 0; b2 < 2; ++b2) {
        int cc = 0;
        #pragma unroll
        for (int ky = 0; ky < 3; ++ky)
        #pragma unroll
        for (int kx = 0; kx < 3; ++kx)
            cc += (int)(wm[(a2 + ky) * 4 + (b2 + kx)] & 1u);
        cnt[a2 * 2 + b2] = cc * 32;
    }
}

// ---------------- fused: conv+pool -> int16 store + BN stats ----------------
template<int OC, int W>
__global__ __launch_bounds__(256) void binconv_store_kernel(
    const uint32_t* __restrict__ sin, const uint32_t* __restrict__ wp,
    const float* __restrict__ alpha, float* __restrict__ partials,
    uint32_t* __restrict__ m16)
{
    constexpr int PW = W / 2;
    constexpr int TOTAL = NB * PW * PW;
    constexpr int G = 4;
    __shared__ uint32_t wl[OC * 9];
    __shared__ float wbuf[4][2 * OC];

    int tid = threadIdx.x;
    for (int i = tid; i < OC * 9; i += 256) wl[i] = wp[i];
    __syncthreads();
    float alp = alpha[0];
    bool useMax = (alp >= 0.f);
    int p = blockIdx.x * 256 + tid;

    uint32_t xw[16], wm[16];
    int cnt[4];
    bc_load_window<W>(sin, p, xw, wm, cnt);

    uint32_t packed[OC / 2];

    for (int g = 0; g < OC / G; ++g) {
        float s[G], s2[G];
        #pragma unroll
        for (int j = 0; j < G; ++j) {
            int oc = g * G + j;
            uint32_t w9[9];
            #pragma unroll
            for (int t = 0; t < 9; ++t) w9[t] = wl[oc * 9 + t];
            int mi = useMax ? INT_MIN : INT_MAX;
            #pragma unroll
            for (int a2 = 0; a2 < 2; ++a2)
            #pragma unroll
            for (int b2 = 0; b2 < 2; ++b2) {
                int pop = 0;
                #pragma unroll
                for (int ky = 0; ky < 3; ++ky)
                #pragma unroll
                for (int kx = 0; kx < 3; ++kx) {
                    int idx = (a2 + ky) * 4 + (b2 + kx);
                    pop += __popc((xw[idx] ^ w9[ky * 3 + kx]) & wm[idx]);
                }
                int vi = cnt[a2 * 2 + b2] - 2 * pop;
                mi = useMax ? max(mi, vi) : min(mi, vi);
            }
            float m = alp * (float)mi;
            s[j] = m; s2[j] = m * m;
            uint32_t h = (uint32_t)(uint16_t)(short)mi;
            if ((oc & 1) == 0) packed[oc >> 1] = h;
            else               packed[oc >> 1] |= h << 16;
        }
        int lane = tid & 63, wv = tid >> 6;
        #pragma unroll
        for (int j = 0; j < G; ++j) {
            float a = s[j], b = s2[j];
            #pragma unroll
            for (int off = 32; off >= 1; off >>= 1) {
                a += __shfl_xor(a, off, 64);
                b += __shfl_xor(b, off, 64);
            }
            if (lane == 0) { wbuf[wv][g * G + j] = a; wbuf[wv][OC + g * G + j] = b; }
        }
    }

    #pragma unroll
    for (int q = 0; q < OC / 2; ++q)
        m16[(size_t)q * TOTAL + p] = packed[q];

    __syncthreads();
    if (tid < 2 * OC)
        partials[blockIdx.x * (2 * OC) + tid] =
            (wbuf[0][tid] + wbuf[1][tid]) + (wbuf[2][tid] + wbuf[3][tid]);
}

// ---------------- fused: load int16 -> BN threshold -> sign pack ----------------
template<int OC, int W>
__global__ __launch_bounds__(256) void binconv_pack_kernel(
    const uint32_t* __restrict__ m16, const float* __restrict__ alpha,
    const float* __restrict__ ss, void* __restrict__ sout)
{
    constexpr int PW = W / 2;
    constexpr int TOTAL = NB * PW * PW;
    __shared__ float Ap[OC], Bp[OC];
    int tid = threadIdx.x;
    if (tid < OC) { Ap[tid] = ss[tid] * alpha[0]; Bp[tid] = ss[OC + tid]; }
    __syncthreads();
    int p = blockIdx.x * 256 + tid;
    uint64_t word = 0;
    #pragma unroll
    for (int q = 0; q < OC / 2; ++q) {
        uint32_t u = m16[(size_t)q * TOTAL + p];
        int m0 = (int)(short)(u & 0xffffu);
        int m1 = (int)(short)(u >> 16);
        float v0 = fmaf(Ap[2 * q],     (float)m0, Bp[2 * q]);
        float v1 = fmaf(Ap[2 * q + 1], (float)m1, Bp[2 * q + 1]);
        word |= (v0 > 0.f ? 1ull : 0ull) << (2 * q);
        word |= (v1 > 0.f ? 1ull : 0ull) << (2 * q + 1);
    }
    if constexpr (OC == 32) ((uint32_t*)sout)[p] = (uint32_t)word;
    else                    ((uint64_t*)sout)[p] = word;
}

// ---------------- fallback (recompute) binary conv + pool ----------------
template<int OC, int W, int MODE, int G>
__global__ __launch_bounds__(256) void binconv_pool_kernel(
    const uint32_t* __restrict__ sin, const uint32_t* __restrict__ wp,
    const float* __restrict__ alpha, const float* __restrict__ ss,
    float* __restrict__ partials, void* __restrict__ sout)
{
    constexpr int PW = W / 2;
    __shared__ uint32_t wl[OC * 9];
    __shared__ float ssl[2 * OC];
    __shared__ float wbuf[4][2 * OC];

    int tid = threadIdx.x;
    for (int i = tid; i < OC * 9; i += 256) wl[i] = wp[i];
    if constexpr (MODE == 1) { if (tid < 2 * OC) ssl[tid] = ss[tid]; }
    __syncthreads();
    float alp = alpha[0];
    int p = blockIdx.x * 256 + tid;

    uint32_t xw[16], wm[16];
    int cnt[4];
    bc_load_window<W>(sin, p, xw, wm, cnt);

    uint64_t word = 0;
    for (int g = 0; g < OC / G; ++g) {
        float s[G], s2[G];
        #pragma unroll
        for (int j = 0; j < G; ++j) {
            int oc = g * G + j;
            uint32_t w9[9];
            #pragma unroll
            for (int t = 0; t < 9; ++t) w9[t] = wl[oc * 9 + t];
            float m = -3.4e38f;
            #pragma unroll
            for (int a2 = 0; a2 < 2; ++a2)
            #pragma unroll
            for (int b2 = 0; b2 < 2; ++b2) {
                int pop = 0;
                #pragma unroll
                for (int ky = 0; ky < 3; ++ky)
                #pragma unroll
                for (int kx = 0; kx < 3; ++kx) {
                    int idx = (a2 + ky) * 4 + (b2 + kx);
                    pop += __popc((xw[idx] ^ w9[ky * 3 + kx]) & wm[idx]);
                }
                float v = alp * (float)(cnt[a2 * 2 + b2] - 2 * pop);
                m = fmaxf(m, v);
            }
            if constexpr (MODE == 0) { s[j] = m; s2[j] = m * m; }
            else {
                float vv = fmaf(ssl[oc], m, ssl[OC + oc]);
                word |= (vv > 0.f ? 1ull : 0ull) << oc;
            }
        }
        if constexpr (MODE == 0) {
            int lane = tid & 63, wv = tid >> 6;
            #pragma unroll
            for (int j = 0; j < G; ++j) {
                float a = s[j], b = s2[j];
                #pragma unroll
                for (int off = 32; off >= 1; off >>= 1) {
                    a += __shfl_xor(a, off, 64);
                    b += __shfl_xor(b, off, 64);
                }
                if (lane == 0) { wbuf[wv][g * G + j] = a; wbuf[wv][OC + g * G + j] = b; }
            }
        }
    }

    if constexpr (MODE == 1) {
        if constexpr (OC == 32) ((uint32_t*)sout)[p] = (uint32_t)word;
        else                    ((uint64_t*)sout)[p] = word;
    } else {
        __syncthreads();
        if (tid < 2 * OC)
            partials[blockIdx.x * (2 * OC) + tid] =
                (wbuf[0][tid] + wbuf[1][tid]) + (wbuf[2][tid] + wbuf[3][tid]);
    }
}

// ---------------- stage 4: binary conv 64->128, slab partials ----------------
__global__ __launch_bounds__(256) void conv4_partial_kernel(
    const uint64_t* __restrict__ s3, const uint64_t* __restrict__ wp4,
    float* __restrict__ p4)
{
    __shared__ uint64_t xt[192];    // 6 rows x 32 cols (halo)
    __shared__ uint64_t wl[1152];
    __shared__ float red[256];
    int b = blockIdx.x;
    int n = b >> 3, s = b & 7;
    int tid = threadIdx.x;
    for (int i = tid; i < 192; i += 256) {
        int row = 4 * s - 1 + (i >> 5);
        int col = i & 31;
        xt[i] = (row >= 0 && row < 32) ? s3[(size_t)n * 1024 + row * 32 + col] : 0ull;
    }
    for (int i = tid; i < 1152; i += 256) wl[i] = wp4[i];
    __syncthreads();
    int oc = tid & 127, h = tid >> 7;
    uint64_t wr[9];
    #pragma unroll
    for (int t = 0; t < 9; ++t) wr[t] = wl[oc * 9 + t];
    int acc = 0;
    #pragma unroll
    for (int ry = 0; ry < 2; ++ry) {
        int lry = 2 * h + ry;
        int y = 4 * s + lry;
        for (int x = 0; x < 32; ++x) {
            int pop = 0, c = 0;
            #pragma unroll
            for (int ky = 0; ky < 3; ++ky) {
                int yy = y + ky - 1;
                if (yy < 0 || yy >= 32) continue;
                int lrow = lry + ky;
                #pragma unroll
                for (int kx = 0; kx < 3; ++kx) {
                    int xx = x + kx - 1;
                    if (xx < 0 || xx >= 32) continue;
                    pop += __popcll(xt[lrow * 32 + xx] ^ wr[ky * 3 + kx]);
                    c += 64;
                }
            }
            acc += c - 2 * pop;
        }
    }
    red[tid] = (float)acc;
    __syncthreads();
    if (tid < 128)
        p4[(size_t)b * 128 + tid] = red[tid] + red[tid + 128];
}

__global__ void mean4_kernel(const float* __restrict__ p4, const float* __restrict__ alpha4,
                             float* __restrict__ mean4)
{
    int t = blockIdx.x * blockDim.x + threadIdx.x;
    if (t >= NB * 128) return;
    int n = t >> 7, oc = t & 127;
    float a = 0.f;
    #pragma unroll
    for (int s = 0; s < 8; ++s)
        a += p4[(size_t)((n * 8 + s) * 128) + oc];
    mean4[t] = a * alpha4[0] * (1.f / 1024.f);
}

__global__ void linear_kernel(const float* __restrict__ mean4, const float* __restrict__ wf,
                              const float* __restrict__ bf, float* __restrict__ out)
{
    int t = blockIdx.x * blockDim.x + threadIdx.x;
    if (t >= 1280) return;
    int n = t / 10, k = t % 10;
    const float* m = mean4 + n * 128;
    const float* w = wf + k * 128;
    float a = bf[k];
    #pragma unroll 4
    for (int i = 0; i < 128; ++i) a = fmaf(m[i], w[i], a);
    out[t] = a;
}

extern "C" void kernel_launch(void* const* d_in, const int* in_sizes, int n_in,
                              void* d_out, int out_size, void* d_ws, size_t ws_size,
                              hipStream_t stream)
{
    const float* x   = (const float*)d_in[0];
    const float* w1  = (const float*)d_in[1];
    const float* b1  = (const float*)d_in[2];
    const float* g1  = (const float*)d_in[3];
    const float* be1 = (const float*)d_in[4];
    const float* w2  = (const float*)d_in[5];
    const float* a2  = (const float*)d_in[6];
    const float* g2  = (const float*)d_in[7];
    const float* be2 = (const float*)d_in[8];
    const float* w3  = (const float*)d_in[9];
    const float* a3  = (const float*)d_in[10];
    const float* g3  = (const float*)d_in[11];
    const float* be3 = (const float*)d_in[12];
    const float* w4  = (const float*)d_in[13];
    const float* a4  = (const float*)d_in[14];
    const float* wf  = (const float*)d_in[15];
    const float* bf  = (const float*)d_in[16];
    float* out = (float*)d_out;

    uint8_t* ws = (uint8_t*)d_ws;
    size_t off = 0;
    auto alloc = [&](size_t bytes) -> void* {
        void* p = ws + off;
        off += (bytes + 255) & ~(size_t)255;
        return p;
    };
    uint32_t* wp2 = (uint32_t*)alloc(288 * 4);
    uint32_t* wp3 = (uint32_t*)alloc(576 * 4);
    uint32_t* wp4 = (uint32_t*)alloc(2304 * 4);
    float* ss1 = (float*)alloc(64 * 4);
    float* ss2 = (float*)alloc(64 * 4);
    float* ss3 = (float*)alloc(128 * 4);
    double* dsums = (double*)alloc(128 * 8);
    uint32_t* s1 = (uint32_t*)alloc((size_t)128 * 128 * 128 * 4);
    uint32_t* s2 = (uint32_t*)alloc((size_t)128 * 64 * 64 * 4);
    uint64_t* s3 = (uint64_t*)alloc((size_t)128 * 32 * 32 * 8);
    float* mean4 = (float*)alloc((size_t)128 * 128 * 4);
    float* p4    = (float*)alloc((size_t)1024 * 128 * 4);
    float* partials = (float*)alloc((size_t)2048 * 64 * 4);
    size_t base_off = off;
    // int16 conv intermediates (fused path)
    uint32_t* m16_2 = (uint32_t*)alloc((size_t)16 * 524288 * 4);  // 33.6 MB
    uint32_t* m16_3 = (uint32_t*)alloc((size_t)32 * 131072 * 4);  // 16.8 MB
    bool fused = (off <= ws_size);
    (void)base_off;

    // pack weight signs
    pack_weights_kernel<<<2, 256, 0, stream>>>(w2, wp2, 32, 1);
    pack_weights_kernel<<<3, 256, 0, stream>>>(w3, wp3, 64, 1);
    pack_weights_kernel<<<9, 256, 0, stream>>>(w4, wp4, 128, 2);

    // stage 1: xcorr stats -> BN scale/shift -> conv+sign+pack
    xcorr_kernel<<<512, 256, 0, stream>>>(x, partials);
    reduce_partials_kernel<54, 64><<<54, 256, 0, stream>>>(partials, 512, dsums);
    compute_ss1_kernel<<<1, 64, 0, stream>>>(dsums, w1, b1, g1, be1, ss1);
    conv1_pack_kernel<<<2048, 256, 0, stream>>>(x, w1, b1, ss1, s1);

    if (fused) {
        // stage 2: conv+store int16 + stats -> BN -> thin pack
        binconv_store_kernel<32, 128><<<2048, 256, 0, stream>>>(s1, wp2, a2, partials, m16_2);
        reduce_partials_kernel<64, 64><<<64, 256, 0, stream>>>(partials, 2048, dsums);
        compute_ss_kernel<32><<<1, 32, 0, stream>>>(dsums, g2, be2, 1.f / 524288.f, ss2);
        binconv_pack_kernel<32, 128><<<2048, 256, 0, stream>>>(m16_2, a2, ss2, (void*)s2);

        // stage 3
        binconv_store_kernel<64, 64><<<512, 256, 0, stream>>>(s2, wp3, a3, partials, m16_3);
        reduce_partials_kernel<128, 128><<<128, 256, 0, stream>>>(partials, 512, dsums);
        compute_ss_kernel<64><<<1, 64, 0, stream>>>(dsums, g3, be3, 1.f / 131072.f, ss3);
        binconv_pack_kernel<64, 64><<<512, 256, 0, stream>>>(m16_3, a3, ss3, (void*)s3);
    } else {
        // fallback: recompute path
        binconv_pool_kernel<32, 128, 0, 4><<<2048, 256, 0, stream>>>(s1, wp2, a2, nullptr, partials, nullptr);
        reduce_partials_kernel<64, 64><<<64, 256, 0, stream>>>(partials, 2048, dsums);
        compute_ss_kernel<32><<<1, 32, 0, stream>>>(dsums, g2, be2, 1.f / 524288.f, ss2);
        binconv_pool_kernel<32, 128, 1, 4><<<2048, 256, 0, stream>>>(s1, wp2, a2, ss2, nullptr, (void*)s2);

        binconv_pool_kernel<64, 64, 0, 4><<<512, 256, 0, stream>>>(s2, wp3, a3, nullptr, partials, nullptr);
        reduce_partials_kernel<128, 128><<<128, 256, 0, stream>>>(partials, 512, dsums);
        compute_ss_kernel<64><<<1, 64, 0, stream>>>(dsums, g3, be3, 1.f / 131072.f, ss3);
        binconv_pool_kernel<64, 64, 1, 4><<<512, 256, 0, stream>>>(s2, wp3, a3, ss3, nullptr, (void*)s3);
    }

    // stage 4: slab partials -> mean -> classifier
    conv4_partial_kernel<<<1024, 256, 0, stream>>>(s3, (const uint64_t*)wp4, p4);
    mean4_kernel<<<64, 256, 0, stream>>>(p4, a4, mean4);
    linear_kernel<<<5, 256, 0, stream>>>(mean4, wf, bf, out);
}